// Round 1
// baseline (1089.036 us; speedup 1.0000x reference)
//
#include <hip/hip_runtime.h>
#include <stdint.h>
#include <stddef.h>

typedef _Float16 f16;
typedef _Float16 half8 __attribute__((ext_vector_type(8)));
typedef float f32x4 __attribute__((ext_vector_type(4)));

constexpr int kB = 4, kSQ = 512, kSK = 1024, kH = 1024, kHeads = 16, kE = 8, kDFF = 4096;
constexpr int kTok = kB * kSQ;  // 2048 gen tokens

// ---------------- fp32 -> fp16 conversion (RNE) ----------------
__global__ void f2h_kernel(const float* __restrict__ src, f16* __restrict__ dst, long n4) {
  long i = (long)blockIdx.x * blockDim.x + threadIdx.x;
  if (i >= n4) return;
  float4 v = ((const float4*)src)[i];
  union { f16 h[4]; uint2 u; } o;
  o.h[0] = (f16)v.x; o.h[1] = (f16)v.y; o.h[2] = (f16)v.z; o.h[3] = (f16)v.w;
  ((uint2*)dst)[i] = o.u;
}

// ---------------- LayerNorm over H=1024, one block (256 thr) per row --------
__global__ __launch_bounds__(256) void ln_kernel(const float* __restrict__ x,
                                                 const float* __restrict__ g,
                                                 const float* __restrict__ b,
                                                 f16* __restrict__ oh, float* __restrict__ of,
                                                 int rows) {
  int row = blockIdx.x;
  if (row >= rows) return;
  int tid = threadIdx.x;
  const float* xr = x + (long)row * kH;
  float4 v = *(const float4*)(xr + tid * 4);
  float s = v.x + v.y + v.z + v.w;
  float s2 = v.x * v.x + v.y * v.y + v.z * v.z + v.w * v.w;
  __shared__ float red[8];
  for (int o = 32; o; o >>= 1) { s += __shfl_down(s, o); s2 += __shfl_down(s2, o); }
  int wv = tid >> 6, lane = tid & 63;
  if (lane == 0) { red[wv] = s; red[4 + wv] = s2; }
  __syncthreads();
  if (tid == 0) {
    red[0] = red[0] + red[1] + red[2] + red[3];
    red[4] = red[4] + red[5] + red[6] + red[7];
  }
  __syncthreads();
  float mean = red[0] * (1.0f / kH);
  float var = red[4] * (1.0f / kH) - mean * mean;
  float rs = rsqrtf(var + 1e-6f);
  float4 gv = *(const float4*)(g + tid * 4);
  float4 bv = *(const float4*)(b + tid * 4);
  float y0 = (v.x - mean) * rs * gv.x + bv.x;
  float y1 = (v.y - mean) * rs * gv.y + bv.y;
  float y2 = (v.z - mean) * rs * gv.z + bv.z;
  float y3 = (v.w - mean) * rs * gv.w + bv.w;
  long base = (long)row * kH + tid * 4;
  if (oh) {
    union { f16 h[4]; uint2 u; } o;
    o.h[0] = (f16)y0; o.h[1] = (f16)y1; o.h[2] = (f16)y2; o.h[3] = (f16)y3;
    *(uint2*)(oh + base) = o.u;
  }
  if (of) { float4 o4 = {y0, y1, y2, y3}; *(float4*)(of + base) = o4; }
}

// ---------------- row softmax over SK=1024, in place, fp16 ----------------
__global__ __launch_bounds__(256) void softmax_kernel(f16* __restrict__ sc) {
  long row = blockIdx.x;
  f16* p = sc + row * kSK;
  int tid = threadIdx.x;
  union { f16 h[4]; uint2 u; } lv;
  lv.u = *(uint2*)(p + tid * 4);
  float v0 = (float)lv.h[0], v1 = (float)lv.h[1], v2 = (float)lv.h[2], v3 = (float)lv.h[3];
  __shared__ float red[8];
  float mx = fmaxf(fmaxf(v0, v1), fmaxf(v2, v3));
  for (int o = 32; o; o >>= 1) mx = fmaxf(mx, __shfl_down(mx, o));
  int wv = tid >> 6, lane = tid & 63;
  if (lane == 0) red[wv] = mx;
  __syncthreads();
  if (tid == 0) red[0] = fmaxf(fmaxf(red[0], red[1]), fmaxf(red[2], red[3]));
  __syncthreads();
  mx = red[0];
  float e0 = __expf(v0 - mx), e1 = __expf(v1 - mx), e2 = __expf(v2 - mx), e3 = __expf(v3 - mx);
  float s = e0 + e1 + e2 + e3;
  for (int o = 32; o; o >>= 1) s += __shfl_down(s, o);
  if (lane == 0) red[4 + wv] = s;
  __syncthreads();
  if (tid == 0) red[4] = red[4] + red[5] + red[6] + red[7];
  __syncthreads();
  float inv = 1.0f / red[4];
  lv.h[0] = (f16)(e0 * inv); lv.h[1] = (f16)(e1 * inv);
  lv.h[2] = (f16)(e2 * inv); lv.h[3] = (f16)(e3 * inv);
  *(uint2*)(p + tid * 4) = lv.u;
}

// ---------------- zero small int buffer ----------------
__global__ void zero_kernel(int* __restrict__ p, int n) {
  int i = blockIdx.x * blockDim.x + threadIdx.x;
  if (i < n) p[i] = 0;
}

// ---------------- router: fp32 logits, first-index argmax, bucket tokens ----
__global__ __launch_bounds__(64) void router_kernel(const float* __restrict__ ca,
                                                    const float* __restrict__ gw,
                                                    const float* __restrict__ gb,
                                                    int* __restrict__ cursors,
                                                    int* __restrict__ list) {
  int t = blockIdx.x;
  int lane = threadIdx.x;
  const float* x = ca + (long)t * kH;
  float acc[kE];
#pragma unroll
  for (int e = 0; e < kE; e++) acc[e] = 0.0f;
  for (int h = lane; h < kH; h += 64) {
    float xv = x[h];
    const float* gr = gw + (long)h * kE;
#pragma unroll
    for (int e = 0; e < kE; e++) acc[e] += xv * gr[e];
  }
#pragma unroll
  for (int e = 0; e < kE; e++)
    for (int o = 32; o; o >>= 1) acc[e] += __shfl_down(acc[e], o);
  if (lane == 0) {
    int best = 0;
    float bv = acc[0] + gb[0];
    for (int e = 1; e < kE; e++) {
      float v = acc[e] + gb[e];
      if (v > bv) { bv = v; best = e; }  // strict > == first-index argmax
    }
    int slot = atomicAdd(&cursors[best], 1);
    list[best * kTok + slot] = t;
  }
}

// ---------------- generic fp16 MFMA GEMM ----------------
// C[M,N] = epilogue(A[M,K] @ B[K,N]); 64x64 tile, BK=32, 4 waves x (2x2) 16x16x32 mfma.
struct GemmP {
  const f16* A; long a_row, a_z1, a_z2;
  const f16* Bm; long b_kstr, b_nstr, b_z1, b_z2; int b_kcontig;
  float* Cf; f16* Ch; long c_row, c_z1, c_z2;
  const float* bias; long bias_z;
  const float* res; long res_row, res_z1, res_z2;
  float alpha; int gelu;
  int M, N, K, zdiv;
  const int* glist; const int* cnt;  // expert-gather mode: z = expert
};

__global__ __launch_bounds__(256) void gemm_kernel(GemmP p) {
  __shared__ f16 As[64][40];  // +8 pad: 16B-aligned rows, conflict break
  __shared__ f16 Bs[64][40];  // stored [n][k]
  int z = blockIdx.z;
  long aoff = 0, boff = 0, coff = 0, roff = 0, biasoff = 0;
  const int* gl = nullptr;
  int Meff = p.M;
  if (p.glist) {
    Meff = p.cnt[z];
    gl = p.glist + (long)z * kTok;
    boff = (long)z * p.b_z2;
    biasoff = (long)z * p.bias_z;
  } else {
    int z1 = z / p.zdiv, z2 = z % p.zdiv;
    aoff = (long)z1 * p.a_z1 + (long)z2 * p.a_z2;
    boff = (long)z1 * p.b_z1 + (long)z2 * p.b_z2;
    coff = (long)z1 * p.c_z1 + (long)z2 * p.c_z2;
    roff = (long)z1 * p.res_z1 + (long)z2 * p.res_z2;
  }
  int m0 = blockIdx.y * 64, n0 = blockIdx.x * 64;
  if (m0 >= Meff) return;

  int tid = threadIdx.x;
  int lane = tid & 63, wave = tid >> 6;
  int wm = (wave >> 1) * 32, wn = (wave & 1) * 32;
  int q = lane >> 4, lo = lane & 15;

  // A staging: 64 rows x 4 k-groups of 8 (16B each)
  int ar = tid >> 2, ak = (tid & 3) << 3;
  int arow = m0 + ar;
  bool a_ok = arow < Meff;
  long a_base = 0;
  if (a_ok) {
    long rr = gl ? (long)gl[arow] : (long)arow;
    a_base = aoff + rr * p.a_row;
  }
  int br, bc;
  if (p.b_kcontig) { br = tid >> 2; bc = (tid & 3) << 3; }   // [n-row][k-col], direct 16B
  else             { br = tid >> 3; bc = (tid & 7) << 3; }   // [k-row][n-col], transpose via LDS

  f32x4 acc[2][2] = {};

  for (int k0 = 0; k0 < p.K; k0 += 32) {
    uint4 av = {0, 0, 0, 0};
    if (a_ok) av = *(const uint4*)(p.A + a_base + k0 + ak);
    *(uint4*)&As[ar][ak] = av;
    if (p.b_kcontig) {
      uint4 bvv = *(const uint4*)(p.Bm + boff + (long)(n0 + br) * p.b_nstr + (k0 + bc));
      *(uint4*)&Bs[br][bc] = bvv;
    } else {
      uint4 bvv = *(const uint4*)(p.Bm + boff + (long)(k0 + br) * p.b_kstr + (n0 + bc));
      union { uint4 u; f16 h[8]; } t; t.u = bvv;
#pragma unroll
      for (int j = 0; j < 8; j++) Bs[bc + j][br] = t.h[j];
    }
    __syncthreads();
#pragma unroll
    for (int ti = 0; ti < 2; ti++) {
      half8 af = *(const half8*)&As[wm + ti * 16 + lo][q * 8];
#pragma unroll
      for (int tj = 0; tj < 2; tj++) {
        half8 bf = *(const half8*)&Bs[wn + tj * 16 + lo][q * 8];
        acc[ti][tj] = __builtin_amdgcn_mfma_f32_16x16x32_f16(af, bf, acc[ti][tj], 0, 0, 0);
      }
    }
    __syncthreads();
  }

#pragma unroll
  for (int ti = 0; ti < 2; ti++) {
#pragma unroll
    for (int tj = 0; tj < 2; tj++) {
#pragma unroll
      for (int r = 0; r < 4; r++) {
        int row = m0 + wm + ti * 16 + q * 4 + r;
        int col = n0 + wn + tj * 16 + lo;
        if (row < Meff) {
          long rr = gl ? (long)gl[row] : (long)row;
          float v = acc[ti][tj][r];
          if (p.bias) v += p.bias[biasoff + col];
          v *= p.alpha;
          if (p.res) v += p.res[roff + rr * p.res_row + col];
          if (p.gelu) v = 0.5f * v * (1.0f + erff(v * 0.70710678118654752f));
          long ci = coff + rr * p.c_row + col;
          if (p.Cf) p.Cf[ci] = v;
          else p.Ch[ci] = (f16)v;
        }
      }
    }
  }
}

extern "C" void kernel_launch(void* const* d_in, const int* in_sizes, int n_in,
                              void* d_out, int out_size, void* d_ws, size_t ws_size,
                              hipStream_t stream) {
  const float* concated = (const float*)d_in[0];
  const float* gen      = (const float*)d_in[1];
  const float* mask     = (const float*)d_in[2];
  const float* ln_g     = (const float*)d_in[3];
  const float* ln_b     = (const float*)d_in[4];
  const float* wq = (const float*)d_in[5];  const float* bq = (const float*)d_in[6];
  const float* wk = (const float*)d_in[7];  const float* bk = (const float*)d_in[8];
  const float* wv = (const float*)d_in[9];  const float* bv = (const float*)d_in[10];
  const float* wo = (const float*)d_in[11]; const float* bo = (const float*)d_in[12];
  const float* gw = (const float*)d_in[13]; const float* gb = (const float*)d_in[14];
  const float* w1 = (const float*)d_in[15]; const float* b1 = (const float*)d_in[16];
  const float* w2 = (const float*)d_in[17]; const float* b2 = (const float*)d_in[18];
  float* out = (float*)d_out;

  size_t off = 0;
  auto alloc = [&](size_t bytes) -> void* {
    void* p = (char*)d_ws + off;
    off += (bytes + 255) & ~(size_t)255;
    return p;
  };
  f16* wq_h  = (f16*)alloc((size_t)kH * kH * 2);
  f16* wk_h  = (f16*)alloc((size_t)kH * kH * 2);
  f16* wv_h  = (f16*)alloc((size_t)kH * kH * 2);
  f16* wo_h  = (f16*)alloc((size_t)kH * kH * 2);
  f16* w1_h  = (f16*)alloc((size_t)kE * kH * kDFF * 2);
  f16* w2_h  = (f16*)alloc((size_t)kE * kDFF * kH * 2);
  f16* lnc_h = (f16*)alloc((size_t)kB * kSK * kH * 2);
  f16* lng_h = (f16*)alloc((size_t)kTok * kH * 2);
  f16* q_h   = (f16*)alloc((size_t)kTok * kH * 2);
  f16* k_h   = (f16*)alloc((size_t)kB * kSK * kH * 2);
  f16* v_h   = (f16*)alloc((size_t)kB * kSK * kH * 2);
  f16* sc_h  = (f16*)alloc((size_t)kB * kHeads * kSQ * kSK * 2);
  f16* ctx_h = (f16*)alloc((size_t)kTok * kH * 2);
  float* ca_f   = (float*)alloc((size_t)kTok * kH * 4);
  float* lnca_f = (float*)alloc((size_t)kTok * kH * 4);
  f16* lnca_h   = (f16*)alloc((size_t)kTok * kH * 2);
  f16* h1_h     = (f16*)alloc((size_t)kTok * kDFF * 2);
  int* cnt_d    = (int*)alloc(kE * 4);
  int* list_d   = (int*)alloc((size_t)kE * kTok * 4);

  auto cdiv = [](long a, long b) { return (int)((a + b - 1) / b); };

  // weight conversion fp32 -> fp16
  {
    long n4 = (long)kH * kH / 4;
    f2h_kernel<<<cdiv(n4, 256), 256, 0, stream>>>(wq, wq_h, n4);
    f2h_kernel<<<cdiv(n4, 256), 256, 0, stream>>>(wk, wk_h, n4);
    f2h_kernel<<<cdiv(n4, 256), 256, 0, stream>>>(wv, wv_h, n4);
    f2h_kernel<<<cdiv(n4, 256), 256, 0, stream>>>(wo, wo_h, n4);
    long nw = (long)kE * kH * kDFF / 4;
    f2h_kernel<<<cdiv(nw, 256), 256, 0, stream>>>(w1, w1_h, nw);
    f2h_kernel<<<cdiv(nw, 256), 256, 0, stream>>>(w2, w2_h, nw);
  }
  // LayerNorms of inputs
  ln_kernel<<<kB * kSK, 256, 0, stream>>>(concated, ln_g, ln_b, lnc_h, nullptr, kB * kSK);
  ln_kernel<<<kTok, 256, 0, stream>>>(gen, ln_g, ln_b, lng_h, nullptr, kTok);

  // Q (1/sqrt(DH)=0.125 folded in), K, V projections
  {
    GemmP p{}; p.A = lng_h; p.a_row = kH;
    p.Bm = wq_h; p.b_kstr = kH; p.b_kcontig = 0;
    p.Ch = q_h; p.c_row = kH; p.bias = bq; p.alpha = 0.125f;
    p.M = kTok; p.N = kH; p.K = kH; p.zdiv = 1;
    gemm_kernel<<<dim3(kH / 64, kTok / 64, 1), 256, 0, stream>>>(p);
  }
  {
    GemmP p{}; p.A = lnc_h; p.a_row = kH;
    p.Bm = wk_h; p.b_kstr = kH; p.b_kcontig = 0;
    p.Ch = k_h; p.c_row = kH; p.bias = bk; p.alpha = 1.0f;
    p.M = kB * kSK; p.N = kH; p.K = kH; p.zdiv = 1;
    gemm_kernel<<<dim3(kH / 64, kB * kSK / 64, 1), 256, 0, stream>>>(p);
  }
  {
    GemmP p{}; p.A = lnc_h; p.a_row = kH;
    p.Bm = wv_h; p.b_kstr = kH; p.b_kcontig = 0;
    p.Ch = v_h; p.c_row = kH; p.bias = bv; p.alpha = 1.0f;
    p.M = kB * kSK; p.N = kH; p.K = kH; p.zdiv = 1;
    gemm_kernel<<<dim3(kH / 64, kB * kSK / 64, 1), 256, 0, stream>>>(p);
  }
  // scores[b,h] = q_slice @ k_slice^T + mask  (fp16 out)
  {
    GemmP p{}; p.A = q_h; p.a_row = kH; p.a_z1 = (long)kSQ * kH; p.a_z2 = 64;
    p.Bm = k_h; p.b_kstr = 1; p.b_nstr = kH; p.b_z1 = (long)kSK * kH; p.b_z2 = 64; p.b_kcontig = 1;
    p.Ch = sc_h; p.c_row = kSK; p.c_z1 = (long)kHeads * kSQ * kSK; p.c_z2 = (long)kSQ * kSK;
    p.res = mask; p.res_row = kSK; p.res_z1 = (long)kSQ * kSK; p.res_z2 = 0;
    p.alpha = 1.0f; p.M = kSQ; p.N = kSK; p.K = 64; p.zdiv = kHeads;
    gemm_kernel<<<dim3(kSK / 64, kSQ / 64, kB * kHeads), 256, 0, stream>>>(p);
  }
  softmax_kernel<<<kB * kHeads * kSQ, 256, 0, stream>>>(sc_h);
  // ctx[b,h] = probs @ v_slice
  {
    GemmP p{}; p.A = sc_h; p.a_row = kSK; p.a_z1 = (long)kHeads * kSQ * kSK; p.a_z2 = (long)kSQ * kSK;
    p.Bm = v_h; p.b_kstr = kH; p.b_z1 = (long)kSK * kH; p.b_z2 = 64; p.b_kcontig = 0;
    p.Ch = ctx_h; p.c_row = kH; p.c_z1 = (long)kSQ * kH; p.c_z2 = 64;
    p.alpha = 1.0f; p.M = kSQ; p.N = 64; p.K = kSK; p.zdiv = kHeads;
    gemm_kernel<<<dim3(1, kSQ / 64, kB * kHeads), 256, 0, stream>>>(p);
  }
  // ca_out = ctx @ wo + bo + gen (fp32 out)
  {
    GemmP p{}; p.A = ctx_h; p.a_row = kH;
    p.Bm = wo_h; p.b_kstr = kH; p.b_kcontig = 0;
    p.Cf = ca_f; p.c_row = kH; p.bias = bo;
    p.res = gen; p.res_row = kH;
    p.alpha = 1.0f; p.M = kTok; p.N = kH; p.K = kH; p.zdiv = 1;
    gemm_kernel<<<dim3(kH / 64, kTok / 64, 1), 256, 0, stream>>>(p);
  }
  // ln_ca (fp32 + fp16)
  ln_kernel<<<kTok, 256, 0, stream>>>(ca_f, ln_g, ln_b, lnca_h, lnca_f, kTok);
  // router (fp32 exact-ish) + expert bucketing
  zero_kernel<<<1, 64, 0, stream>>>(cnt_d, kE);
  router_kernel<<<kTok, 64, 0, stream>>>(ca_f, gw, gb, cnt_d, list_d);
  // FFN expert GEMM 1: h1 = gelu(ln_ca @ w1[e] + b1[e])
  {
    GemmP p{}; p.A = lnca_h; p.a_row = kH;
    p.Bm = w1_h; p.b_kstr = kDFF; p.b_z2 = (long)kH * kDFF; p.b_kcontig = 0;
    p.Ch = h1_h; p.c_row = kDFF; p.bias = b1; p.bias_z = kDFF;
    p.alpha = 1.0f; p.gelu = 1; p.M = kTok; p.N = kDFF; p.K = kH; p.zdiv = 1;
    p.glist = list_d; p.cnt = cnt_d;
    gemm_kernel<<<dim3(kDFF / 64, kTok / 64, kE), 256, 0, stream>>>(p);
  }
  // FFN expert GEMM 2: out = h1 @ w2[e] + b2[e] + ln_ca (fp32, scatter to d_out)
  {
    GemmP p{}; p.A = h1_h; p.a_row = kDFF;
    p.Bm = w2_h; p.b_kstr = kH; p.b_z2 = (long)kDFF * kH; p.b_kcontig = 0;
    p.Cf = out; p.c_row = kH; p.bias = b2; p.bias_z = kH;
    p.res = lnca_f; p.res_row = kH;
    p.alpha = 1.0f; p.M = kTok; p.N = kH; p.K = kDFF; p.zdiv = 1;
    p.glist = list_d; p.cnt = cnt_d;
    gemm_kernel<<<dim3(kH / 64, kTok / 64, kE), 256, 0, stream>>>(p);
  }
}